// Round 6
// baseline (227.471 us; speedup 1.0000x reference)
//
#include <hip/hip_runtime.h>

#define D_IN 128
#define D_HID 256
#define D_OUT 128
#define NBIN 10240          // padded bin count (n=10000)
#define HB 128              // histogram/scatter blocks

typedef __attribute__((ext_vector_type(8))) unsigned short ushort8v;
typedef __attribute__((ext_vector_type(4))) unsigned short ushort4v;
typedef __attribute__((ext_vector_type(8))) short short8v;
typedef __attribute__((ext_vector_type(4))) float f32x4;

__device__ __forceinline__ unsigned short f2bf(float f) {
    unsigned u = __float_as_uint(f);
    unsigned r = (u + 0x7fffu + ((u >> 16) & 1u)) >> 16;
    return (unsigned short)r;
}
__device__ __forceinline__ float bf2f(unsigned short b) {
    return __uint_as_float((unsigned)b << 16);
}

// ---------------- pass A: per-block LDS histograms (no global atomics) ----------------

__global__ __launch_bounds__(256) void k_hist(const int* __restrict__ src, const int* __restrict__ dst,
                                              int* __restrict__ psrc, int* __restrict__ pdst,
                                              int E, int EPB) {
    __shared__ int hs[NBIN];
    __shared__ int hd[NBIN];
    int b = blockIdx.x, t = threadIdx.x;
    for (int i = t; i < NBIN; i += 256) { hs[i] = 0; hd[i] = 0; }
    __syncthreads();
    int beg = b * EPB, end = beg + EPB; if (end > E) end = E;
    for (int e = beg + t; e < end; e += 256) {
        atomicAdd(&hs[src[e]], 1);
        atomicAdd(&hd[dst[e]], 1);
    }
    __syncthreads();
    for (int i = t; i < NBIN; i += 256) {
        psrc[b * NBIN + i] = hs[i];
        pdst[b * NBIN + i] = hd[i];
    }
}

// ---------------- pass B: column sums -> dis, cnt; pdst -> per-block exclusive prefix ----

__global__ __launch_bounds__(256) void k_colsum(const int* __restrict__ psrc, int* __restrict__ pdst,
                                                float* __restrict__ dis, int* __restrict__ cnt) {
    int bin = blockIdx.x * 256 + threadIdx.x;
    if (bin >= NBIN) return;
    int degs = 0;
    for (int b = 0; b < HB; ++b) degs += psrc[b * NBIN + bin];
    int c = 0;
    for (int b = 0; b < HB; ++b) {
        int v = pdst[b * NBIN + bin];
        pdst[b * NBIN + bin] = c;
        c += v;
    }
    dis[bin] = degs > 0 ? rsqrtf((float)degs) : 0.f;
    cnt[bin] = c;
}

// ---------------- exclusive scan (single block) ----------------

__global__ void k_scan(const int* __restrict__ cnt, int* __restrict__ off, int n, int E) {
    __shared__ int sums[256];
    int t = threadIdx.x;
    int chunk = (n + 255) / 256;
    int beg = t * chunk;
    int end = beg + chunk; if (end > n) end = n;
    int s = 0;
    for (int i = beg; i < end; ++i) s += cnt[i];
    sums[t] = s;
    __syncthreads();
    if (t == 0) {
        int running = 0;
        for (int i = 0; i < 256; ++i) { int tmp = sums[i]; sums[i] = running; running += tmp; }
        off[n] = E;
    }
    __syncthreads();
    int pre = sums[t];
    for (int i = beg; i < end; ++i) { off[i] = pre; pre += cnt[i]; }
}

// ---------------- pass C: scatter into dst-sorted order (LDS rank, no global atomics) ----

__global__ __launch_bounds__(256) void k_scatter2(const int* __restrict__ src, const int* __restrict__ dst,
                                                  const float* __restrict__ dis, const int* __restrict__ off,
                                                  const int* __restrict__ pfx,
                                                  int* __restrict__ srcs, float* __restrict__ norms,
                                                  int E, int EPB) {
    __shared__ int lcnt[NBIN];
    int b = blockIdx.x, t = threadIdx.x;
    for (int i = t; i < NBIN; i += 256) lcnt[i] = 0;
    __syncthreads();
    int beg = b * EPB, end = beg + EPB; if (end > E) end = E;
    const int* pf = pfx + b * NBIN;
    for (int e = beg + t; e < end; e += 256) {
        int s = src[e], d = dst[e];
        int r = atomicAdd(&lcnt[d], 1);    // LDS atomic only
        int pos = off[d] + pf[d] + r;
        srcs[pos] = s;
        norms[pos] = -(dis[s] * dis[d]);
    }
}

// ---------------- fp32 -> bf16 convert ----------------

__global__ void k_f2bf(const float* __restrict__ in, unsigned short* __restrict__ out, int nElem) {
    int i = (blockIdx.x * blockDim.x + threadIdx.x) * 4;
    if (i < nElem) {
        float4 v = *reinterpret_cast<const float4*>(&in[i]);
        ushort4v o;
        o[0] = f2bf(v.x); o[1] = f2bf(v.y); o[2] = f2bf(v.z); o[3] = f2bf(v.w);
        *reinterpret_cast<ushort4v*>(&out[i]) = o;
    }
}

// ---------------- 6 weight transposes in one dispatch ----------------

struct WtrArgs {
    const float* W[6];
    unsigned short* T[6];
    int K[6];
    int N[6];
};

__global__ __launch_bounds__(256) void k_wtr6(WtrArgs args) {
    __shared__ float tile[32][33];
    int z = blockIdx.z;
    const float* W = args.W[z];
    unsigned short* Wt = args.T[z];
    int K = args.K[z], N = args.N[z];
    int k0 = blockIdx.x * 32, n0 = blockIdx.y * 32;
    if (k0 >= K || n0 >= N) return;
    int tx = threadIdx.x & 31, ty = threadIdx.x >> 5;   // 32x8
    for (int i = ty; i < 32; i += 8) tile[i][tx] = W[(size_t)(k0 + i) * N + n0 + tx];
    __syncthreads();
    for (int i = ty; i < 32; i += 8) Wt[(size_t)(n0 + i) * K + k0 + tx] = f2bf(tile[tx][i]);
}

// ---------------- CSR gather-aggregate, bf16 input, column-chunked ----------------
// TPN=32 lanes/node (4 cols, 8-B gathers), ILP-8: 8 gathers in flight per lane.
// Non-temporal edge-list loads keep the x-chunk resident in L2.

template<int D, bool STBF, bool STF32>
__global__ __launch_bounds__(256) void k_agg_bf(const int* __restrict__ off,
                                                const int* __restrict__ srcs,
                                                const float* __restrict__ norms,
                                                const unsigned short* __restrict__ xb,
                                                unsigned short* __restrict__ outb,
                                                float* __restrict__ outf, int n) {
    const int CHUNK = 128;
    const int TPN = CHUNK / 4;       // 32 lanes per node
    const int NPB = 256 / TPN;       // 8 nodes per block
    int tid = threadIdx.x;
    int node = blockIdx.x * NPB + tid / TPN;
    if (node >= n) return;
    int cbase = blockIdx.y * CHUNK + (tid % TPN) * 4;
    int i = off[node], end = off[node + 1];
    float acc[4] = {};
    for (; i + 7 < end; i += 8) {
        int s[8]; float nn[8]; ushort4v v[8];
        #pragma unroll
        for (int u = 0; u < 8; ++u) {
            s[u] = __builtin_nontemporal_load(&srcs[i + u]);
            nn[u] = __builtin_nontemporal_load(&norms[i + u]);
        }
        #pragma unroll
        for (int u = 0; u < 8; ++u)
            v[u] = *reinterpret_cast<const ushort4v*>(&xb[(size_t)s[u] * D + cbase]);
        #pragma unroll
        for (int u = 0; u < 8; ++u)
            #pragma unroll
            for (int j = 0; j < 4; ++j)
                acc[j] += nn[u] * bf2f(v[u][j]);
    }
    for (; i + 1 < end; i += 2) {
        int s0 = __builtin_nontemporal_load(&srcs[i]);
        int s1 = __builtin_nontemporal_load(&srcs[i + 1]);
        float n0 = __builtin_nontemporal_load(&norms[i]);
        float n1 = __builtin_nontemporal_load(&norms[i + 1]);
        ushort4v v0 = *reinterpret_cast<const ushort4v*>(&xb[(size_t)s0 * D + cbase]);
        ushort4v v1 = *reinterpret_cast<const ushort4v*>(&xb[(size_t)s1 * D + cbase]);
        #pragma unroll
        for (int j = 0; j < 4; ++j)
            acc[j] += n0 * bf2f(v0[j]) + n1 * bf2f(v1[j]);
    }
    if (i < end) {
        int s0 = srcs[i]; float n0 = norms[i];
        ushort4v v0 = *reinterpret_cast<const ushort4v*>(&xb[(size_t)s0 * D + cbase]);
        #pragma unroll
        for (int j = 0; j < 4; ++j)
            acc[j] += n0 * bf2f(v0[j]);
    }
    if (STBF) {
        ushort4v ob;
        #pragma unroll
        for (int j = 0; j < 4; ++j) ob[j] = f2bf(acc[j]);
        *reinterpret_cast<ushort4v*>(&outb[(size_t)node * D + cbase]) = ob;
    }
    if (STF32) {
        float4 o0;
        o0.x = acc[0]; o0.y = acc[1]; o0.z = acc[2]; o0.w = acc[3];
        *reinterpret_cast<float4*>(&outf[(size_t)node * D + cbase]) = o0;
    }
}

// ---------------- MFMA bf16 GEMM ----------------
// C[M,N] = epi( A1@W0t' (+ A2@W1t') ), A:[M][K] bf16, Wt:[N][K] bf16.
// BM=64 x BN=128 tile, 4 waves (2x2), each wave 32x64, 16x16x32 MFMA, fp32 accum.

template<int K, bool RELU, bool HAS_B2, bool HAS_ADD, bool HAS_BIAS, bool ST_BF, bool ST_F32>
__global__ __launch_bounds__(256) void k_gemm_mfma(
        const unsigned short* __restrict__ A1, const unsigned short* __restrict__ W0t,
        const unsigned short* __restrict__ A2, const unsigned short* __restrict__ W1t,
        const float* __restrict__ ADDV, const float* __restrict__ bias,
        float* __restrict__ C, unsigned short* __restrict__ Cb, int M, int N) {
    const int LDT = 40;                       // lds row stride (bf16), padded
    __shared__ unsigned short As[64 * LDT];
    __shared__ unsigned short Bs[128 * LDT];
    int tid = threadIdx.x, lane = tid & 63, wave = tid >> 6;
    int wm = wave >> 1, wn = wave & 1;
    int row0 = blockIdx.x * 64, col0 = blockIdx.y * 128;
    f32x4 acc[2][4];
    #pragma unroll
    for (int i = 0; i < 2; ++i)
        #pragma unroll
        for (int j = 0; j < 4; ++j)
            acc[i][j] = (f32x4){0.f, 0.f, 0.f, 0.f};

    int aRow = wm * 32 + (lane & 15);
    int bRow = wn * 64 + (lane & 15);
    int kOff = (lane >> 4) * 8;

    const int npass = HAS_B2 ? 2 : 1;
    for (int pass = 0; pass < npass; ++pass) {
        const unsigned short* A = pass ? A2 : A1;
        const unsigned short* W = pass ? W1t : W0t;
        for (int k0 = 0; k0 < K; k0 += 32) {
            {   // stage A: 64 rows x 32 k, 1 ushort8 per thread
                int r = tid >> 2, c = (tid & 3) * 8;
                int gr = row0 + r; if (gr >= M) gr = M - 1;
                ushort8v va = *reinterpret_cast<const ushort8v*>(&A[(size_t)gr * K + k0 + c]);
                *reinterpret_cast<ushort8v*>(&As[r * LDT + c]) = va;
            }
            {   // stage B: 128 rows x 32 k, 2 ushort8 per thread
                int f = tid;
                #pragma unroll
                for (int l = 0; l < 2; ++l, f += 256) {
                    int r = f >> 2, c = (f & 3) * 8;
                    ushort8v vb = *reinterpret_cast<const ushort8v*>(&W[(size_t)(col0 + r) * K + k0 + c]);
                    *reinterpret_cast<ushort8v*>(&Bs[r * LDT + c]) = vb;
                }
            }
            __syncthreads();
            short8v a[2], bb[4];
            #pragma unroll
            for (int i = 0; i < 2; ++i)
                a[i] = *reinterpret_cast<const short8v*>(&As[(aRow + i * 16) * LDT + kOff]);
            #pragma unroll
            for (int i = 0; i < 4; ++i)
                bb[i] = *reinterpret_cast<const short8v*>(&Bs[(bRow + i * 16) * LDT + kOff]);
            #pragma unroll
            for (int mi = 0; mi < 2; ++mi)
                #pragma unroll
                for (int ni = 0; ni < 4; ++ni)
                    acc[mi][ni] = __builtin_amdgcn_mfma_f32_16x16x32_bf16(a[mi], bb[ni], acc[mi][ni], 0, 0, 0);
            __syncthreads();
        }
    }

    // epilogue: C/D layout col = lane&15, row = (lane>>4)*4 + reg
    int colBase = col0 + wn * 64 + (lane & 15);
    int rowSub = (lane >> 4) * 4;
    #pragma unroll
    for (int mi = 0; mi < 2; ++mi) {
        int rowF = row0 + wm * 32 + mi * 16 + rowSub;
        #pragma unroll
        for (int r = 0; r < 4; ++r) {
            int gr = rowF + r;
            if (gr < M) {
                #pragma unroll
                for (int ni = 0; ni < 4; ++ni) {
                    int gc = colBase + ni * 16;
                    float v = acc[mi][ni][r];
                    if (HAS_BIAS) v += bias[gc];
                    if (HAS_ADD)  v += ADDV[(size_t)gr * N + gc];
                    if (RELU)     v = fmaxf(v, 0.f);
                    if (ST_F32)   C[(size_t)gr * N + gc] = v;
                    if (ST_BF)    Cb[(size_t)gr * N + gc] = f2bf(v);
                }
            }
        }
    }
}

// ---------------- launch ----------------

extern "C" void kernel_launch(void* const* d_in, const int* in_sizes, int n_in,
                              void* d_out, int out_size, void* d_ws, size_t ws_size,
                              hipStream_t stream) {
    const float* x   = (const float*)d_in[0];
    const int*   ei  = (const int*)d_in[1];
    const float* W01 = (const float*)d_in[3];
    const float* W11 = (const float*)d_in[4];
    const float* b1  = (const float*)d_in[5];
    const float* W02 = (const float*)d_in[6];
    const float* W12 = (const float*)d_in[7];
    const float* b2  = (const float*)d_in[8];
    const float* W03 = (const float*)d_in[9];
    const float* W13 = (const float*)d_in[10];
    const float* b3  = (const float*)d_in[11];
    float* out = (float*)d_out;

    const int n = in_sizes[0] / D_IN;   // 10000
    const int E = in_sizes[1] / 2;      // 640000
    const int* src = ei;
    const int* dst = ei + E;
    const int EPB = (E + HB - 1) / HB;  // 5000

    char* wsb = (char*)d_ws;
    float* dis   = (float*)wsb;                   wsb += NBIN * 4;
    int*   cnt   = (int*)wsb;                     wsb += NBIN * 4;
    int*   off   = (int*)wsb;                     wsb += (NBIN + 16) * 4;
    int*   psrc  = (int*)wsb;                     wsb += (size_t)HB * NBIN * 4;
    int*   pdst  = (int*)wsb;                     wsb += (size_t)HB * NBIN * 4;
    int*   srcs  = (int*)wsb;                     wsb += (size_t)E * 4;
    float* norms = (float*)wsb;                   wsb += (size_t)E * 4;
    unsigned short* txb  = (unsigned short*)wsb;  wsb += (size_t)n * D_HID * 2;
    float*          tx32 = (float*)wsb;           wsb += (size_t)n * D_OUT * 4;
    unsigned short* x_bf = (unsigned short*)wsb;  wsb += (size_t)n * D_IN * 2;
    unsigned short* h1_bf = (unsigned short*)wsb; wsb += (size_t)n * D_HID * 2;
    unsigned short* h2_bf = (unsigned short*)wsb; wsb += (size_t)n * D_HID * 2;
    unsigned short* y3_bf = (unsigned short*)wsb; wsb += (size_t)n * D_OUT * 2;
    unsigned short* W01t = (unsigned short*)wsb;  wsb += (size_t)D_IN  * D_HID * 2;
    unsigned short* W11t = (unsigned short*)wsb;  wsb += (size_t)D_IN  * D_HID * 2;
    unsigned short* W02t = (unsigned short*)wsb;  wsb += (size_t)D_HID * D_HID * 2;
    unsigned short* W12t = (unsigned short*)wsb;  wsb += (size_t)D_HID * D_HID * 2;
    unsigned short* W03t = (unsigned short*)wsb;  wsb += (size_t)D_HID * D_OUT * 2;
    unsigned short* W13t = (unsigned short*)wsb;  wsb += (size_t)D_HID * D_OUT * 2;

    const int gmx = (n + 63) / 64;      // 157 M-tiles
    const int gax = (n + 7) / 8;        // 1250 aggregate x-blocks

    // ---- CSR build (atomic-free) + normalization ----
    k_hist<<<HB, 256, 0, stream>>>(src, dst, psrc, pdst, E, EPB);
    k_colsum<<<NBIN / 256, 256, 0, stream>>>(psrc, pdst, dis, cnt);
    k_scan<<<1, 256, 0, stream>>>(cnt, off, n, E);
    k_scatter2<<<HB, 256, 0, stream>>>(src, dst, dis, off, pdst, srcs, norms, E, EPB);

    // ---- bf16 conversions ----
    k_f2bf<<<(n * D_IN / 4 + 255) / 256, 256, 0, stream>>>(x, x_bf, n * D_IN);
    {
        WtrArgs wa;
        wa.W[0] = W01; wa.T[0] = W01t; wa.K[0] = D_IN;  wa.N[0] = D_HID;
        wa.W[1] = W11; wa.T[1] = W11t; wa.K[1] = D_IN;  wa.N[1] = D_HID;
        wa.W[2] = W02; wa.T[2] = W02t; wa.K[2] = D_HID; wa.N[2] = D_HID;
        wa.W[3] = W12; wa.T[3] = W12t; wa.K[3] = D_HID; wa.N[3] = D_HID;
        wa.W[4] = W03; wa.T[4] = W03t; wa.K[4] = D_HID; wa.N[4] = D_OUT;
        wa.W[5] = W13; wa.T[5] = W13t; wa.K[5] = D_HID; wa.N[5] = D_OUT;
        k_wtr6<<<dim3(8, 8, 6), 256, 0, stream>>>(wa);
    }

    // ---- layer 1: h1 = relu(x@W01 + (A x)@W11 + b1) ----
    k_agg_bf<D_IN, true, false><<<dim3(gax, 1), 256, 0, stream>>>(
        off, srcs, norms, x_bf, txb, nullptr, n);
    k_gemm_mfma<D_IN, true, true, false, true, true, false><<<dim3(gmx, D_HID / 128), 256, 0, stream>>>(
        x_bf, W01t, txb, W11t, nullptr, b1, nullptr, h1_bf, n, D_HID);

    // ---- layer 2: h2 = relu(h1@W02 + (A h1)@W12 + b2) ----
    k_agg_bf<D_HID, true, false><<<dim3(gax, 2), 256, 0, stream>>>(
        off, srcs, norms, h1_bf, txb, nullptr, n);
    k_gemm_mfma<D_HID, true, true, false, true, true, false><<<dim3(gmx, D_HID / 128), 256, 0, stream>>>(
        h1_bf, W02t, txb, W12t, nullptr, b2, nullptr, h2_bf, n, D_HID);

    // ---- layer 3: out = h2@W03 + A (h2@W13) + b3 ----
    k_gemm_mfma<D_HID, false, false, false, false, true, false><<<dim3(gmx, D_OUT / 128), 256, 0, stream>>>(
        h2_bf, W13t, nullptr, nullptr, nullptr, nullptr, nullptr, y3_bf, n, D_OUT);
    k_agg_bf<D_OUT, false, true><<<dim3(gax, 1), 256, 0, stream>>>(
        off, srcs, norms, y3_bf, nullptr, tx32, n);
    k_gemm_mfma<D_HID, false, false, true, true, false, true><<<dim3(gmx, D_OUT / 128), 256, 0, stream>>>(
        h2_bf, W03t, nullptr, nullptr, tx32, b3, out, nullptr, n, D_OUT);
}

// Round 7
// 189.023 us; speedup vs baseline: 1.2034x; 1.2034x over previous
//
#include <hip/hip_runtime.h>

#define D_IN 128
#define D_HID 256
#define D_OUT 128
#define NBIN 10240          // padded bin count (n=10000)
#define HB 128              // histogram/scatter blocks

typedef __attribute__((ext_vector_type(8))) unsigned short ushort8v;
typedef __attribute__((ext_vector_type(4))) unsigned short ushort4v;
typedef __attribute__((ext_vector_type(8))) short short8v;
typedef __attribute__((ext_vector_type(4))) float f32x4;

__device__ __forceinline__ unsigned short f2bf(float f) {
    unsigned u = __float_as_uint(f);
    unsigned r = (u + 0x7fffu + ((u >> 16) & 1u)) >> 16;
    return (unsigned short)r;
}
__device__ __forceinline__ float bf2f(unsigned short b) {
    return __uint_as_float((unsigned)b << 16);
}

// ---------------- pass A: per-block LDS histograms (no global atomics) ----------------

__global__ __launch_bounds__(256) void k_hist(const int* __restrict__ src, const int* __restrict__ dst,
                                              int* __restrict__ psrc, int* __restrict__ pdst,
                                              int E, int EPB) {
    __shared__ int hs[NBIN];
    __shared__ int hd[NBIN];
    int b = blockIdx.x, t = threadIdx.x;
    for (int i = t; i < NBIN; i += 256) { hs[i] = 0; hd[i] = 0; }
    __syncthreads();
    int beg = b * EPB, end = beg + EPB; if (end > E) end = E;
    for (int e = beg + t; e < end; e += 256) {
        atomicAdd(&hs[src[e]], 1);
        atomicAdd(&hd[dst[e]], 1);
    }
    __syncthreads();
    for (int i = t; i < NBIN; i += 256) {
        psrc[b * NBIN + i] = hs[i];
        pdst[b * NBIN + i] = hd[i];
    }
}

// ---------------- pass B: column sums -> dis, cnt; pdst -> per-block exclusive prefix ----

__global__ __launch_bounds__(256) void k_colsum(const int* __restrict__ psrc, int* __restrict__ pdst,
                                                float* __restrict__ dis, int* __restrict__ cnt) {
    int bin = blockIdx.x * 256 + threadIdx.x;
    if (bin >= NBIN) return;
    int degs = 0;
    for (int b = 0; b < HB; ++b) degs += psrc[b * NBIN + bin];
    int c = 0;
    for (int b = 0; b < HB; ++b) {
        int v = pdst[b * NBIN + bin];
        pdst[b * NBIN + bin] = c;
        c += v;
    }
    dis[bin] = degs > 0 ? rsqrtf((float)degs) : 0.f;
    cnt[bin] = c;
}

// ---------------- exclusive scan (single block) ----------------

__global__ void k_scan(const int* __restrict__ cnt, int* __restrict__ off, int n, int E) {
    __shared__ int sums[256];
    int t = threadIdx.x;
    int chunk = (n + 255) / 256;
    int beg = t * chunk;
    int end = beg + chunk; if (end > n) end = n;
    int s = 0;
    for (int i = beg; i < end; ++i) s += cnt[i];
    sums[t] = s;
    __syncthreads();
    if (t == 0) {
        int running = 0;
        for (int i = 0; i < 256; ++i) { int tmp = sums[i]; sums[i] = running; running += tmp; }
        off[n] = E;
    }
    __syncthreads();
    int pre = sums[t];
    for (int i = beg; i < end; ++i) { off[i] = pre; pre += cnt[i]; }
}

// ---------------- pass C: scatter into dst-sorted order (LDS rank, no global atomics) ----
// writes packed edge records: int2{src, norm_bits}

__global__ __launch_bounds__(256) void k_scatter2(const int* __restrict__ src, const int* __restrict__ dst,
                                                  const float* __restrict__ dis, const int* __restrict__ off,
                                                  const int* __restrict__ pfx,
                                                  int2* __restrict__ edges, int E, int EPB) {
    __shared__ int lcnt[NBIN];
    int b = blockIdx.x, t = threadIdx.x;
    for (int i = t; i < NBIN; i += 256) lcnt[i] = 0;
    __syncthreads();
    int beg = b * EPB, end = beg + EPB; if (end > E) end = E;
    const int* pf = pfx + b * NBIN;
    for (int e = beg + t; e < end; e += 256) {
        int s = src[e], d = dst[e];
        int r = atomicAdd(&lcnt[d], 1);    // LDS atomic only
        int pos = off[d] + pf[d] + r;
        float nv = -(dis[s] * dis[d]);
        edges[pos] = make_int2(s, __float_as_int(nv));
    }
}

// ---------------- fp32 -> bf16 convert ----------------

__global__ void k_f2bf(const float* __restrict__ in, unsigned short* __restrict__ out, int nElem) {
    int i = (blockIdx.x * blockDim.x + threadIdx.x) * 4;
    if (i < nElem) {
        float4 v = *reinterpret_cast<const float4*>(&in[i]);
        ushort4v o;
        o[0] = f2bf(v.x); o[1] = f2bf(v.y); o[2] = f2bf(v.z); o[3] = f2bf(v.w);
        *reinterpret_cast<ushort4v*>(&out[i]) = o;
    }
}

// ---------------- 6 weight transposes in one dispatch ----------------

struct WtrArgs {
    const float* W[6];
    unsigned short* T[6];
    int K[6];
    int N[6];
};

__global__ __launch_bounds__(256) void k_wtr6(WtrArgs args) {
    __shared__ float tile[32][33];
    int z = blockIdx.z;
    const float* W = args.W[z];
    unsigned short* Wt = args.T[z];
    int K = args.K[z], N = args.N[z];
    int k0 = blockIdx.x * 32, n0 = blockIdx.y * 32;
    if (k0 >= K || n0 >= N) return;
    int tx = threadIdx.x & 31, ty = threadIdx.x >> 5;   // 32x8
    for (int i = ty; i < 32; i += 8) tile[i][tx] = W[(size_t)(k0 + i) * N + n0 + tx];
    __syncthreads();
    for (int i = ty; i < 32; i += 8) Wt[(size_t)(n0 + i) * K + k0 + tx] = f2bf(tile[tx][i]);
}

// ---------------- CSR gather-aggregate, bf16 input, column-chunked ----------------
// TPN=16 lanes/node (8 cols, 16-B gathers), ILP-8: 128 B in flight per lane.
// Packed int2 edge records: one 8-B load per edge.

template<int D, bool STBF, bool STF32>
__global__ __launch_bounds__(256) void k_agg_bf(const int* __restrict__ off,
                                                const int2* __restrict__ edges,
                                                const unsigned short* __restrict__ xb,
                                                unsigned short* __restrict__ outb,
                                                float* __restrict__ outf, int n) {
    const int CHUNK = 128;
    const int TPN = CHUNK / 8;       // 16 lanes per node
    const int NPB = 256 / TPN;       // 16 nodes per block
    int tid = threadIdx.x;
    int node = blockIdx.x * NPB + tid / TPN;
    if (node >= n) return;
    int cbase = blockIdx.y * CHUNK + (tid % TPN) * 8;
    int i = off[node], end = off[node + 1];
    float acc[8] = {};
    for (; i + 7 < end; i += 8) {
        int2 e[8];
        #pragma unroll
        for (int u = 0; u < 8; ++u) e[u] = edges[i + u];
        ushort8v v[8];
        #pragma unroll
        for (int u = 0; u < 8; ++u)
            v[u] = *reinterpret_cast<const ushort8v*>(&xb[(size_t)e[u].x * D + cbase]);
        #pragma unroll
        for (int u = 0; u < 8; ++u) {
            float nv = __int_as_float(e[u].y);
            #pragma unroll
            for (int j = 0; j < 8; ++j)
                acc[j] += nv * bf2f(v[u][j]);
        }
    }
    for (; i + 1 < end; i += 2) {
        int2 e0 = edges[i], e1 = edges[i + 1];
        ushort8v v0 = *reinterpret_cast<const ushort8v*>(&xb[(size_t)e0.x * D + cbase]);
        ushort8v v1 = *reinterpret_cast<const ushort8v*>(&xb[(size_t)e1.x * D + cbase]);
        float n0 = __int_as_float(e0.y), n1 = __int_as_float(e1.y);
        #pragma unroll
        for (int j = 0; j < 8; ++j)
            acc[j] += n0 * bf2f(v0[j]) + n1 * bf2f(v1[j]);
    }
    if (i < end) {
        int2 e0 = edges[i];
        float n0 = __int_as_float(e0.y);
        ushort8v v0 = *reinterpret_cast<const ushort8v*>(&xb[(size_t)e0.x * D + cbase]);
        #pragma unroll
        for (int j = 0; j < 8; ++j)
            acc[j] += n0 * bf2f(v0[j]);
    }
    if (STBF) {
        ushort8v ob;
        #pragma unroll
        for (int j = 0; j < 8; ++j) ob[j] = f2bf(acc[j]);
        *reinterpret_cast<ushort8v*>(&outb[(size_t)node * D + cbase]) = ob;
    }
    if (STF32) {
        float4 o0, o1;
        o0.x = acc[0]; o0.y = acc[1]; o0.z = acc[2]; o0.w = acc[3];
        o1.x = acc[4]; o1.y = acc[5]; o1.z = acc[6]; o1.w = acc[7];
        *reinterpret_cast<float4*>(&outf[(size_t)node * D + cbase]) = o0;
        *reinterpret_cast<float4*>(&outf[(size_t)node * D + cbase + 4]) = o1;
    }
}

// ---------------- MFMA bf16 GEMM ----------------
// C[M,N] = epi( A1@W0t' (+ A2@W1t') ), A:[M][K] bf16, Wt:[N][K] bf16.
// BM=64 x BN=128 tile, 4 waves (2x2), each wave 32x64, 16x16x32 MFMA, fp32 accum.

template<int K, bool RELU, bool HAS_B2, bool HAS_ADD, bool HAS_BIAS, bool ST_BF, bool ST_F32>
__global__ __launch_bounds__(256) void k_gemm_mfma(
        const unsigned short* __restrict__ A1, const unsigned short* __restrict__ W0t,
        const unsigned short* __restrict__ A2, const unsigned short* __restrict__ W1t,
        const float* __restrict__ ADDV, const float* __restrict__ bias,
        float* __restrict__ C, unsigned short* __restrict__ Cb, int M, int N) {
    const int LDT = 40;                       // lds row stride (bf16), padded
    __shared__ unsigned short As[64 * LDT];
    __shared__ unsigned short Bs[128 * LDT];
    int tid = threadIdx.x, lane = tid & 63, wave = tid >> 6;
    int wm = wave >> 1, wn = wave & 1;
    int row0 = blockIdx.x * 64, col0 = blockIdx.y * 128;
    f32x4 acc[2][4];
    #pragma unroll
    for (int i = 0; i < 2; ++i)
        #pragma unroll
        for (int j = 0; j < 4; ++j)
            acc[i][j] = (f32x4){0.f, 0.f, 0.f, 0.f};

    int aRow = wm * 32 + (lane & 15);
    int bRow = wn * 64 + (lane & 15);
    int kOff = (lane >> 4) * 8;

    const int npass = HAS_B2 ? 2 : 1;
    for (int pass = 0; pass < npass; ++pass) {
        const unsigned short* A = pass ? A2 : A1;
        const unsigned short* W = pass ? W1t : W0t;
        for (int k0 = 0; k0 < K; k0 += 32) {
            {   // stage A: 64 rows x 32 k, 1 ushort8 per thread
                int r = tid >> 2, c = (tid & 3) * 8;
                int gr = row0 + r; if (gr >= M) gr = M - 1;
                ushort8v va = *reinterpret_cast<const ushort8v*>(&A[(size_t)gr * K + k0 + c]);
                *reinterpret_cast<ushort8v*>(&As[r * LDT + c]) = va;
            }
            {   // stage B: 128 rows x 32 k, 2 ushort8 per thread
                int f = tid;
                #pragma unroll
                for (int l = 0; l < 2; ++l, f += 256) {
                    int r = f >> 2, c = (f & 3) * 8;
                    ushort8v vb = *reinterpret_cast<const ushort8v*>(&W[(size_t)(col0 + r) * K + k0 + c]);
                    *reinterpret_cast<ushort8v*>(&Bs[r * LDT + c]) = vb;
                }
            }
            __syncthreads();
            short8v a[2], bb[4];
            #pragma unroll
            for (int i = 0; i < 2; ++i)
                a[i] = *reinterpret_cast<const short8v*>(&As[(aRow + i * 16) * LDT + kOff]);
            #pragma unroll
            for (int i = 0; i < 4; ++i)
                bb[i] = *reinterpret_cast<const short8v*>(&Bs[(bRow + i * 16) * LDT + kOff]);
            #pragma unroll
            for (int mi = 0; mi < 2; ++mi)
                #pragma unroll
                for (int ni = 0; ni < 4; ++ni)
                    acc[mi][ni] = __builtin_amdgcn_mfma_f32_16x16x32_bf16(a[mi], bb[ni], acc[mi][ni], 0, 0, 0);
            __syncthreads();
        }
    }

    // epilogue: C/D layout col = lane&15, row = (lane>>4)*4 + reg
    int colBase = col0 + wn * 64 + (lane & 15);
    int rowSub = (lane >> 4) * 4;
    #pragma unroll
    for (int mi = 0; mi < 2; ++mi) {
        int rowF = row0 + wm * 32 + mi * 16 + rowSub;
        #pragma unroll
        for (int r = 0; r < 4; ++r) {
            int gr = rowF + r;
            if (gr < M) {
                #pragma unroll
                for (int ni = 0; ni < 4; ++ni) {
                    int gc = colBase + ni * 16;
                    float v = acc[mi][ni][r];
                    if (HAS_BIAS) v += bias[gc];
                    if (HAS_ADD)  v += ADDV[(size_t)gr * N + gc];
                    if (RELU)     v = fmaxf(v, 0.f);
                    if (ST_F32)   C[(size_t)gr * N + gc] = v;
                    if (ST_BF)    Cb[(size_t)gr * N + gc] = f2bf(v);
                }
            }
        }
    }
}

// ---------------- launch ----------------

extern "C" void kernel_launch(void* const* d_in, const int* in_sizes, int n_in,
                              void* d_out, int out_size, void* d_ws, size_t ws_size,
                              hipStream_t stream) {
    const float* x   = (const float*)d_in[0];
    const int*   ei  = (const int*)d_in[1];
    const float* W01 = (const float*)d_in[3];
    const float* W11 = (const float*)d_in[4];
    const float* b1  = (const float*)d_in[5];
    const float* W02 = (const float*)d_in[6];
    const float* W12 = (const float*)d_in[7];
    const float* b2  = (const float*)d_in[8];
    const float* W03 = (const float*)d_in[9];
    const float* W13 = (const float*)d_in[10];
    const float* b3  = (const float*)d_in[11];
    float* out = (float*)d_out;

    const int n = in_sizes[0] / D_IN;   // 10000
    const int E = in_sizes[1] / 2;      // 640000
    const int* src = ei;
    const int* dst = ei + E;
    const int EPB = (E + HB - 1) / HB;  // 5000

    char* wsb = (char*)d_ws;
    float* dis   = (float*)wsb;                   wsb += NBIN * 4;
    int*   cnt   = (int*)wsb;                     wsb += NBIN * 4;
    int*   off   = (int*)wsb;                     wsb += (NBIN + 16) * 4;
    int*   psrc  = (int*)wsb;                     wsb += (size_t)HB * NBIN * 4;
    int*   pdst  = (int*)wsb;                     wsb += (size_t)HB * NBIN * 4;
    int2*  edges = (int2*)wsb;                    wsb += (size_t)E * 8;
    unsigned short* txb  = (unsigned short*)wsb;  wsb += (size_t)n * D_HID * 2;
    float*          tx32 = (float*)wsb;           wsb += (size_t)n * D_OUT * 4;
    unsigned short* x_bf = (unsigned short*)wsb;  wsb += (size_t)n * D_IN * 2;
    unsigned short* h1_bf = (unsigned short*)wsb; wsb += (size_t)n * D_HID * 2;
    unsigned short* h2_bf = (unsigned short*)wsb; wsb += (size_t)n * D_HID * 2;
    unsigned short* y3_bf = (unsigned short*)wsb; wsb += (size_t)n * D_OUT * 2;
    unsigned short* W01t = (unsigned short*)wsb;  wsb += (size_t)D_IN  * D_HID * 2;
    unsigned short* W11t = (unsigned short*)wsb;  wsb += (size_t)D_IN  * D_HID * 2;
    unsigned short* W02t = (unsigned short*)wsb;  wsb += (size_t)D_HID * D_HID * 2;
    unsigned short* W12t = (unsigned short*)wsb;  wsb += (size_t)D_HID * D_HID * 2;
    unsigned short* W03t = (unsigned short*)wsb;  wsb += (size_t)D_HID * D_OUT * 2;
    unsigned short* W13t = (unsigned short*)wsb;  wsb += (size_t)D_HID * D_OUT * 2;

    const int gmx = (n + 63) / 64;      // 157 M-tiles
    const int gax = (n + 15) / 16;      // 625 aggregate x-blocks

    // ---- CSR build (atomic-free) + normalization ----
    k_hist<<<HB, 256, 0, stream>>>(src, dst, psrc, pdst, E, EPB);
    k_colsum<<<NBIN / 256, 256, 0, stream>>>(psrc, pdst, dis, cnt);
    k_scan<<<1, 256, 0, stream>>>(cnt, off, n, E);
    k_scatter2<<<HB, 256, 0, stream>>>(src, dst, dis, off, pdst, edges, E, EPB);

    // ---- bf16 conversions ----
    k_f2bf<<<(n * D_IN / 4 + 255) / 256, 256, 0, stream>>>(x, x_bf, n * D_IN);
    {
        WtrArgs wa;
        wa.W[0] = W01; wa.T[0] = W01t; wa.K[0] = D_IN;  wa.N[0] = D_HID;
        wa.W[1] = W11; wa.T[1] = W11t; wa.K[1] = D_IN;  wa.N[1] = D_HID;
        wa.W[2] = W02; wa.T[2] = W02t; wa.K[2] = D_HID; wa.N[2] = D_HID;
        wa.W[3] = W12; wa.T[3] = W12t; wa.K[3] = D_HID; wa.N[3] = D_HID;
        wa.W[4] = W03; wa.T[4] = W03t; wa.K[4] = D_HID; wa.N[4] = D_OUT;
        wa.W[5] = W13; wa.T[5] = W13t; wa.K[5] = D_HID; wa.N[5] = D_OUT;
        k_wtr6<<<dim3(8, 8, 6), 256, 0, stream>>>(wa);
    }

    // ---- layer 1: h1 = relu(x@W01 + (A x)@W11 + b1) ----
    k_agg_bf<D_IN, true, false><<<dim3(gax, 1), 256, 0, stream>>>(
        off, edges, x_bf, txb, nullptr, n);
    k_gemm_mfma<D_IN, true, true, false, true, true, false><<<dim3(gmx, D_HID / 128), 256, 0, stream>>>(
        x_bf, W01t, txb, W11t, nullptr, b1, nullptr, h1_bf, n, D_HID);

    // ---- layer 2: h2 = relu(h1@W02 + (A h1)@W12 + b2) ----
    k_agg_bf<D_HID, true, false><<<dim3(gax, 2), 256, 0, stream>>>(
        off, edges, h1_bf, txb, nullptr, n);
    k_gemm_mfma<D_HID, true, true, false, true, true, false><<<dim3(gmx, D_HID / 128), 256, 0, stream>>>(
        h1_bf, W02t, txb, W12t, nullptr, b2, nullptr, h2_bf, n, D_HID);

    // ---- layer 3: out = h2@W03 + A (h2@W13) + b3 ----
    k_gemm_mfma<D_HID, false, false, false, false, true, false><<<dim3(gmx, D_OUT / 128), 256, 0, stream>>>(
        h2_bf, W13t, nullptr, nullptr, nullptr, nullptr, nullptr, y3_bf, n, D_OUT);
    k_agg_bf<D_OUT, false, true><<<dim3(gax, 1), 256, 0, stream>>>(
        off, edges, y3_bf, nullptr, tx32, n);
    k_gemm_mfma<D_HID, false, false, true, true, false, true><<<dim3(gmx, D_OUT / 128), 256, 0, stream>>>(
        h2_bf, W03t, nullptr, nullptr, tx32, b3, out, nullptr, n, D_OUT);
}

// Round 8
// 178.882 us; speedup vs baseline: 1.2716x; 1.0567x over previous
//
#include <hip/hip_runtime.h>

#define D_IN 128
#define D_HID 256
#define D_OUT 128
#define NBIN 10240          // padded bin count (n=10000)
#define HB 128              // histogram/scatter blocks

typedef __attribute__((ext_vector_type(8))) unsigned short ushort8v;
typedef __attribute__((ext_vector_type(4))) unsigned short ushort4v;
typedef __attribute__((ext_vector_type(8))) short short8v;
typedef __attribute__((ext_vector_type(4))) float f32x4;

__device__ __forceinline__ unsigned short f2bf(float f) {
    unsigned u = __float_as_uint(f);
    unsigned r = (u + 0x7fffu + ((u >> 16) & 1u)) >> 16;
    return (unsigned short)r;
}
__device__ __forceinline__ float bf2f(unsigned short b) {
    return __uint_as_float((unsigned)b << 16);
}

// ---------------- pass A: per-block LDS histograms (no global atomics) ----------------
// partial counts fit ushort (<= EPB=5000)

__global__ __launch_bounds__(256) void k_hist(const int* __restrict__ src, const int* __restrict__ dst,
                                              unsigned short* __restrict__ psrc,
                                              unsigned short* __restrict__ pdst,
                                              int E, int EPB) {
    __shared__ int hs[NBIN];
    __shared__ int hd[NBIN];
    int b = blockIdx.x, t = threadIdx.x;
    for (int i = t; i < NBIN; i += 256) { hs[i] = 0; hd[i] = 0; }
    __syncthreads();
    int beg = b * EPB, end = beg + EPB; if (end > E) end = E;
    for (int e = beg + t; e < end; e += 256) {
        atomicAdd(&hs[src[e]], 1);
        atomicAdd(&hd[dst[e]], 1);
    }
    __syncthreads();
    for (int i = t; i < NBIN; i += 256) {
        psrc[(size_t)b * NBIN + i] = (unsigned short)hs[i];
        pdst[(size_t)b * NBIN + i] = (unsigned short)hd[i];
    }
}

// ---------------- pass B: column sums -> dis, cnt; pdst -> per-block exclusive prefix ----
// per-bin total degree ~<=150 -> prefixes fit ushort comfortably

__global__ __launch_bounds__(256) void k_colsum(const unsigned short* __restrict__ psrc,
                                                unsigned short* __restrict__ pdst,
                                                float* __restrict__ dis, int* __restrict__ cnt) {
    int bin = blockIdx.x * 256 + threadIdx.x;
    if (bin >= NBIN) return;
    int degs = 0;
    for (int b = 0; b < HB; ++b) degs += psrc[(size_t)b * NBIN + bin];
    int c = 0;
    for (int b = 0; b < HB; ++b) {
        int v = pdst[(size_t)b * NBIN + bin];
        pdst[(size_t)b * NBIN + bin] = (unsigned short)c;
        c += v;
    }
    dis[bin] = degs > 0 ? rsqrtf((float)degs) : 0.f;
    cnt[bin] = c;
}

// ---------------- exclusive scan (single block) ----------------

__global__ void k_scan(const int* __restrict__ cnt, int* __restrict__ off, int n, int E) {
    __shared__ int sums[256];
    int t = threadIdx.x;
    int chunk = (n + 255) / 256;
    int beg = t * chunk;
    int end = beg + chunk; if (end > n) end = n;
    int s = 0;
    for (int i = beg; i < end; ++i) s += cnt[i];
    sums[t] = s;
    __syncthreads();
    if (t == 0) {
        int running = 0;
        for (int i = 0; i < 256; ++i) { int tmp = sums[i]; sums[i] = running; running += tmp; }
        off[n] = E;
    }
    __syncthreads();
    int pre = sums[t];
    for (int i = beg; i < end; ++i) { off[i] = pre; pre += cnt[i]; }
}

// ---------------- pass C: scatter into dst-sorted order (LDS rank, no global atomics) ----

__global__ __launch_bounds__(256) void k_scatter2(const int* __restrict__ src, const int* __restrict__ dst,
                                                  const float* __restrict__ dis, const int* __restrict__ off,
                                                  const unsigned short* __restrict__ pfx,
                                                  int2* __restrict__ edges, int E, int EPB) {
    __shared__ int lcnt[NBIN];
    int b = blockIdx.x, t = threadIdx.x;
    for (int i = t; i < NBIN; i += 256) lcnt[i] = 0;
    __syncthreads();
    int beg = b * EPB, end = beg + EPB; if (end > E) end = E;
    const unsigned short* pf = pfx + (size_t)b * NBIN;
    for (int e = beg + t; e < end; e += 256) {
        int s = src[e], d = dst[e];
        int r = atomicAdd(&lcnt[d], 1);    // LDS atomic only
        int pos = off[d] + (int)pf[d] + r;
        float nv = -(dis[s] * dis[d]);
        edges[pos] = make_int2(s, __float_as_int(nv));
    }
}

// ---------------- weight transposes (z=0..5) + x f32->bf16 (z=6), one dispatch ----------------

struct WtrArgs {
    const float* W[6];
    unsigned short* T[6];
    int K[6];
    int N[6];
    const float* xin;
    unsigned short* xout;
    int nElem;
};

__global__ __launch_bounds__(256) void k_wtr7(WtrArgs args) {
    __shared__ float tile[32][33];
    int z = blockIdx.z;
    if (z == 6) {
        int bid = blockIdx.y * 8 + blockIdx.x;
        int stride = 64 * 256 * 4;
        for (int i = (bid * 256 + threadIdx.x) * 4; i < args.nElem; i += stride) {
            float4 v = *reinterpret_cast<const float4*>(&args.xin[i]);
            ushort4v o;
            o[0] = f2bf(v.x); o[1] = f2bf(v.y); o[2] = f2bf(v.z); o[3] = f2bf(v.w);
            *reinterpret_cast<ushort4v*>(&args.xout[i]) = o;
        }
        return;
    }
    const float* W = args.W[z];
    unsigned short* Wt = args.T[z];
    int K = args.K[z], N = args.N[z];
    int k0 = blockIdx.x * 32, n0 = blockIdx.y * 32;
    if (k0 >= K || n0 >= N) return;
    int tx = threadIdx.x & 31, ty = threadIdx.x >> 5;   // 32x8
    for (int i = ty; i < 32; i += 8) tile[i][tx] = W[(size_t)(k0 + i) * N + n0 + tx];
    __syncthreads();
    for (int i = ty; i < 32; i += 8) Wt[(size_t)(n0 + i) * K + k0 + tx] = f2bf(tile[tx][i]);
}

// ---------------- CSR gather-aggregate, bf16 input, column-chunked ----------------
// TPN=16 lanes/node (8 cols, 16-B gathers), ILP-8: 128 B in flight per lane.
// ADDB: outf = base + acc (fuses the layer-3 final add).

template<int D, bool STBF, bool STF32, bool ADDB>
__global__ __launch_bounds__(256) void k_agg_bf(const int* __restrict__ off,
                                                const int2* __restrict__ edges,
                                                const unsigned short* __restrict__ xb,
                                                unsigned short* __restrict__ outb,
                                                float* __restrict__ outf,
                                                const float* __restrict__ base, int n) {
    const int CHUNK = 128;
    const int TPN = CHUNK / 8;       // 16 lanes per node
    const int NPB = 256 / TPN;       // 16 nodes per block
    int tid = threadIdx.x;
    int node = blockIdx.x * NPB + tid / TPN;
    if (node >= n) return;
    int cbase = blockIdx.y * CHUNK + (tid % TPN) * 8;
    int i = off[node], end = off[node + 1];
    float acc[8] = {};
    for (; i + 7 < end; i += 8) {
        int2 e[8];
        #pragma unroll
        for (int u = 0; u < 8; ++u) e[u] = edges[i + u];
        ushort8v v[8];
        #pragma unroll
        for (int u = 0; u < 8; ++u)
            v[u] = *reinterpret_cast<const ushort8v*>(&xb[(size_t)e[u].x * D + cbase]);
        #pragma unroll
        for (int u = 0; u < 8; ++u) {
            float nv = __int_as_float(e[u].y);
            #pragma unroll
            for (int j = 0; j < 8; ++j)
                acc[j] += nv * bf2f(v[u][j]);
        }
    }
    for (; i + 1 < end; i += 2) {
        int2 e0 = edges[i], e1 = edges[i + 1];
        ushort8v v0 = *reinterpret_cast<const ushort8v*>(&xb[(size_t)e0.x * D + cbase]);
        ushort8v v1 = *reinterpret_cast<const ushort8v*>(&xb[(size_t)e1.x * D + cbase]);
        float n0 = __int_as_float(e0.y), n1 = __int_as_float(e1.y);
        #pragma unroll
        for (int j = 0; j < 8; ++j)
            acc[j] += n0 * bf2f(v0[j]) + n1 * bf2f(v1[j]);
    }
    if (i < end) {
        int2 e0 = edges[i];
        float n0 = __int_as_float(e0.y);
        ushort8v v0 = *reinterpret_cast<const ushort8v*>(&xb[(size_t)e0.x * D + cbase]);
        #pragma unroll
        for (int j = 0; j < 8; ++j)
            acc[j] += n0 * bf2f(v0[j]);
    }
    if (ADDB) {
        float4 b0 = *reinterpret_cast<const float4*>(&base[(size_t)node * D + cbase]);
        float4 b1 = *reinterpret_cast<const float4*>(&base[(size_t)node * D + cbase + 4]);
        acc[0] += b0.x; acc[1] += b0.y; acc[2] += b0.z; acc[3] += b0.w;
        acc[4] += b1.x; acc[5] += b1.y; acc[6] += b1.z; acc[7] += b1.w;
    }
    if (STBF) {
        ushort8v ob;
        #pragma unroll
        for (int j = 0; j < 8; ++j) ob[j] = f2bf(acc[j]);
        *reinterpret_cast<ushort8v*>(&outb[(size_t)node * D + cbase]) = ob;
    }
    if (STF32) {
        float4 o0, o1;
        o0.x = acc[0]; o0.y = acc[1]; o0.z = acc[2]; o0.w = acc[3];
        o1.x = acc[4]; o1.y = acc[5]; o1.z = acc[6]; o1.w = acc[7];
        *reinterpret_cast<float4*>(&outf[(size_t)node * D + cbase]) = o0;
        *reinterpret_cast<float4*>(&outf[(size_t)node * D + cbase + 4]) = o1;
    }
}

// ---------------- MFMA bf16 GEMM, BK=64 ----------------
// C[M,N] = epi( A1@W0t' (+ A2@W1t') ), A:[M][K] bf16, Wt:[N][K] bf16.
// BM=64 x BN=128 tile, 4 waves (2x2), each wave 32x64, 16x16x32 MFMA, fp32 accum.

#define LDT 72   // lds row stride (bf16): 144 B -> ds_read_b128 2-way (free)

template<int K, bool RELU, bool HAS_B2, bool HAS_BIAS, bool ST_BF, bool ST_F32>
__global__ __launch_bounds__(256) void k_gemm_mfma(
        const unsigned short* __restrict__ A1, const unsigned short* __restrict__ W0t,
        const unsigned short* __restrict__ A2, const unsigned short* __restrict__ W1t,
        const float* __restrict__ bias,
        float* __restrict__ C, unsigned short* __restrict__ Cb, int M, int N) {
    __shared__ unsigned short As[64 * LDT];
    __shared__ unsigned short Bs[128 * LDT];
    int tid = threadIdx.x, lane = tid & 63, wave = tid >> 6;
    int wm = wave >> 1, wn = wave & 1;
    int row0 = blockIdx.x * 64, col0 = blockIdx.y * 128;
    f32x4 acc[2][4];
    #pragma unroll
    for (int i = 0; i < 2; ++i)
        #pragma unroll
        for (int j = 0; j < 4; ++j)
            acc[i][j] = (f32x4){0.f, 0.f, 0.f, 0.f};

    int aRow = wm * 32 + (lane & 15);
    int bRow = wn * 64 + (lane & 15);
    int kOff = (lane >> 4) * 8;
    int sr = tid >> 2, sc = (tid & 3) * 8;      // staging coords
    int gra = row0 + sr; if (gra >= M) gra = M - 1;

    const int npass = HAS_B2 ? 2 : 1;
    for (int pass = 0; pass < npass; ++pass) {
        const unsigned short* A = pass ? A2 : A1;
        const unsigned short* W = pass ? W1t : W0t;
        for (int k0 = 0; k0 < K; k0 += 64) {
            // stage A: 64 rows x 64 k (2 ushort8 / thread)
            #pragma unroll
            for (int h = 0; h < 2; ++h) {
                ushort8v va = *reinterpret_cast<const ushort8v*>(&A[(size_t)gra * K + k0 + sc + h * 32]);
                *reinterpret_cast<ushort8v*>(&As[sr * LDT + sc + h * 32]) = va;
            }
            // stage B: 128 rows x 64 k (4 ushort8 / thread)
            #pragma unroll
            for (int g = 0; g < 2; ++g)
                #pragma unroll
                for (int h = 0; h < 2; ++h) {
                    int r = sr + g * 64;
                    ushort8v vb = *reinterpret_cast<const ushort8v*>(&W[(size_t)(col0 + r) * K + k0 + sc + h * 32]);
                    *reinterpret_cast<ushort8v*>(&Bs[r * LDT + sc + h * 32]) = vb;
                }
            __syncthreads();
            #pragma unroll
            for (int kk = 0; kk < 2; ++kk) {
                int ko = kOff + kk * 32;
                short8v a[2], bb[4];
                #pragma unroll
                for (int i = 0; i < 2; ++i)
                    a[i] = *reinterpret_cast<const short8v*>(&As[(aRow + i * 16) * LDT + ko]);
                #pragma unroll
                for (int i = 0; i < 4; ++i)
                    bb[i] = *reinterpret_cast<const short8v*>(&Bs[(bRow + i * 16) * LDT + ko]);
                #pragma unroll
                for (int mi = 0; mi < 2; ++mi)
                    #pragma unroll
                    for (int ni = 0; ni < 4; ++ni)
                        acc[mi][ni] = __builtin_amdgcn_mfma_f32_16x16x32_bf16(a[mi], bb[ni], acc[mi][ni], 0, 0, 0);
            }
            __syncthreads();
        }
    }

    // epilogue: C/D layout col = lane&15, row = (lane>>4)*4 + reg
    int colBase = col0 + wn * 64 + (lane & 15);
    int rowSub = (lane >> 4) * 4;
    #pragma unroll
    for (int mi = 0; mi < 2; ++mi) {
        int rowF = row0 + wm * 32 + mi * 16 + rowSub;
        #pragma unroll
        for (int r = 0; r < 4; ++r) {
            int gr = rowF + r;
            if (gr < M) {
                #pragma unroll
                for (int ni = 0; ni < 4; ++ni) {
                    int gc = colBase + ni * 16;
                    float v = acc[mi][ni][r];
                    if (HAS_BIAS) v += bias[gc];
                    if (RELU)     v = fmaxf(v, 0.f);
                    if (ST_F32)   C[(size_t)gr * N + gc] = v;
                    if (ST_BF)    Cb[(size_t)gr * N + gc] = f2bf(v);
                }
            }
        }
    }
}

// ---------------- dual GEMM for layer 3 ----------------
// blockIdx.y==0: part = h2@W03 + b3 (fp32); blockIdx.y==1: y3 = h2@W13 (bf16).

template<int K>
__global__ __launch_bounds__(256) void k_gemm_dual(
        const unsigned short* __restrict__ A1, const unsigned short* __restrict__ W03t,
        const unsigned short* __restrict__ W13t, const float* __restrict__ bias,
        float* __restrict__ part, unsigned short* __restrict__ y3b, int M) {
    const int N = 128;
    __shared__ unsigned short As[64 * LDT];
    __shared__ unsigned short Bs[128 * LDT];
    int tid = threadIdx.x, lane = tid & 63, wave = tid >> 6;
    int wm = wave >> 1, wn = wave & 1;
    int row0 = blockIdx.x * 64;
    const unsigned short* W = blockIdx.y ? W13t : W03t;
    f32x4 acc[2][4];
    #pragma unroll
    for (int i = 0; i < 2; ++i)
        #pragma unroll
        for (int j = 0; j < 4; ++j)
            acc[i][j] = (f32x4){0.f, 0.f, 0.f, 0.f};

    int aRow = wm * 32 + (lane & 15);
    int bRow = wn * 64 + (lane & 15);
    int kOff = (lane >> 4) * 8;
    int sr = tid >> 2, sc = (tid & 3) * 8;
    int gra = row0 + sr; if (gra >= M) gra = M - 1;

    for (int k0 = 0; k0 < K; k0 += 64) {
        #pragma unroll
        for (int h = 0; h < 2; ++h) {
            ushort8v va = *reinterpret_cast<const ushort8v*>(&A1[(size_t)gra * K + k0 + sc + h * 32]);
            *reinterpret_cast<ushort8v*>(&As[sr * LDT + sc + h * 32]) = va;
        }
        #pragma unroll
        for (int g = 0; g < 2; ++g)
            #pragma unroll
            for (int h = 0; h < 2; ++h) {
                int r = sr + g * 64;
                ushort8v vb = *reinterpret_cast<const ushort8v*>(&W[(size_t)r * K + k0 + sc + h * 32]);
                *reinterpret_cast<ushort8v*>(&Bs[r * LDT + sc + h * 32]) = vb;
            }
        __syncthreads();
        #pragma unroll
        for (int kk = 0; kk < 2; ++kk) {
            int ko = kOff + kk * 32;
            short8v a[2], bb[4];
            #pragma unroll
            for (int i = 0; i < 2; ++i)
                a[i] = *reinterpret_cast<const short8v*>(&As[(aRow + i * 16) * LDT + ko]);
            #pragma unroll
            for (int i = 0; i < 4; ++i)
                bb[i] = *reinterpret_cast<const short8v*>(&Bs[(bRow + i * 16) * LDT + ko]);
            #pragma unroll
            for (int mi = 0; mi < 2; ++mi)
                #pragma unroll
                for (int ni = 0; ni < 4; ++ni)
                    acc[mi][ni] = __builtin_amdgcn_mfma_f32_16x16x32_bf16(a[mi], bb[ni], acc[mi][ni], 0, 0, 0);
        }
        __syncthreads();
    }

    int colBase = wn * 64 + (lane & 15);
    int rowSub = (lane >> 4) * 4;
    bool isPart = (blockIdx.y == 0);
    #pragma unroll
    for (int mi = 0; mi < 2; ++mi) {
        int rowF = row0 + wm * 32 + mi * 16 + rowSub;
        #pragma unroll
        for (int r = 0; r < 4; ++r) {
            int gr = rowF + r;
            if (gr < M) {
                #pragma unroll
                for (int ni = 0; ni < 4; ++ni) {
                    int gc = colBase + ni * 16;
                    float v = acc[mi][ni][r];
                    if (isPart) part[(size_t)gr * N + gc] = v + bias[gc];
                    else        y3b[(size_t)gr * N + gc] = f2bf(v);
                }
            }
        }
    }
}

// ---------------- launch ----------------

extern "C" void kernel_launch(void* const* d_in, const int* in_sizes, int n_in,
                              void* d_out, int out_size, void* d_ws, size_t ws_size,
                              hipStream_t stream) {
    const float* x   = (const float*)d_in[0];
    const int*   ei  = (const int*)d_in[1];
    const float* W01 = (const float*)d_in[3];
    const float* W11 = (const float*)d_in[4];
    const float* b1  = (const float*)d_in[5];
    const float* W02 = (const float*)d_in[6];
    const float* W12 = (const float*)d_in[7];
    const float* b2  = (const float*)d_in[8];
    const float* W03 = (const float*)d_in[9];
    const float* W13 = (const float*)d_in[10];
    const float* b3  = (const float*)d_in[11];
    float* out = (float*)d_out;

    const int n = in_sizes[0] / D_IN;   // 10000
    const int E = in_sizes[1] / 2;      // 640000
    const int* src = ei;
    const int* dst = ei + E;
    const int EPB = (E + HB - 1) / HB;  // 5000

    char* wsb = (char*)d_ws;
    float* dis   = (float*)wsb;                   wsb += NBIN * 4;
    int*   cnt   = (int*)wsb;                     wsb += NBIN * 4;
    int*   off   = (int*)wsb;                     wsb += (NBIN + 16) * 4;
    unsigned short* psrc = (unsigned short*)wsb;  wsb += (size_t)HB * NBIN * 2;
    unsigned short* pdst = (unsigned short*)wsb;  wsb += (size_t)HB * NBIN * 2;
    int2*  edges = (int2*)wsb;                    wsb += (size_t)E * 8;
    unsigned short* txb  = (unsigned short*)wsb;  wsb += (size_t)n * D_HID * 2;
    float*          part = (float*)wsb;           wsb += (size_t)n * D_OUT * 4;
    unsigned short* x_bf = (unsigned short*)wsb;  wsb += (size_t)n * D_IN * 2;
    unsigned short* h1_bf = (unsigned short*)wsb; wsb += (size_t)n * D_HID * 2;
    unsigned short* h2_bf = (unsigned short*)wsb; wsb += (size_t)n * D_HID * 2;
    unsigned short* y3_bf = (unsigned short*)wsb; wsb += (size_t)n * D_OUT * 2;
    unsigned short* W01t = (unsigned short*)wsb;  wsb += (size_t)D_IN  * D_HID * 2;
    unsigned short* W11t = (unsigned short*)wsb;  wsb += (size_t)D_IN  * D_HID * 2;
    unsigned short* W02t = (unsigned short*)wsb;  wsb += (size_t)D_HID * D_HID * 2;
    unsigned short* W12t = (unsigned short*)wsb;  wsb += (size_t)D_HID * D_HID * 2;
    unsigned short* W03t = (unsigned short*)wsb;  wsb += (size_t)D_HID * D_OUT * 2;
    unsigned short* W13t = (unsigned short*)wsb;  wsb += (size_t)D_HID * D_OUT * 2;

    const int gmx = (n + 63) / 64;      // 157 M-tiles
    const int gax = (n + 15) / 16;      // 625 aggregate x-blocks

    // ---- CSR build (atomic-free) + normalization ----
    k_hist<<<HB, 256, 0, stream>>>(src, dst, psrc, pdst, E, EPB);
    k_colsum<<<NBIN / 256, 256, 0, stream>>>(psrc, pdst, dis, cnt);
    k_scan<<<1, 256, 0, stream>>>(cnt, off, n, E);
    k_scatter2<<<HB, 256, 0, stream>>>(src, dst, dis, off, pdst, edges, E, EPB);

    // ---- bf16 conversions: 6 weight transposes + x convert, one dispatch ----
    {
        WtrArgs wa;
        wa.W[0] = W01; wa.T[0] = W01t; wa.K[0] = D_IN;  wa.N[0] = D_HID;
        wa.W[1] = W11; wa.T[1] = W11t; wa.K[1] = D_IN;  wa.N[1] = D_HID;
        wa.W[2] = W02; wa.T[2] = W02t; wa.K[2] = D_HID; wa.N[2] = D_HID;
        wa.W[3] = W12; wa.T[3] = W12t; wa.K[3] = D_HID; wa.N[3] = D_HID;
        wa.W[4] = W03; wa.T[4] = W03t; wa.K[4] = D_HID; wa.N[4] = D_OUT;
        wa.W[5] = W13; wa.T[5] = W13t; wa.K[5] = D_HID; wa.N[5] = D_OUT;
        wa.xin = x; wa.xout = x_bf; wa.nElem = n * D_IN;
        k_wtr7<<<dim3(8, 8, 7), 256, 0, stream>>>(wa);
    }

    // ---- layer 1: h1 = relu(x@W01 + (A x)@W11 + b1) ----
    k_agg_bf<D_IN, true, false, false><<<dim3(gax, 1), 256, 0, stream>>>(
        off, edges, x_bf, txb, nullptr, nullptr, n);
    k_gemm_mfma<D_IN, true, true, true, true, false><<<dim3(gmx, D_HID / 128), 256, 0, stream>>>(
        x_bf, W01t, txb, W11t, b1, nullptr, h1_bf, n, D_HID);

    // ---- layer 2: h2 = relu(h1@W02 + (A h1)@W12 + b2) ----
    k_agg_bf<D_HID, true, false, false><<<dim3(gax, 2), 256, 0, stream>>>(
        off, edges, h1_bf, txb, nullptr, nullptr, n);
    k_gemm_mfma<D_HID, true, true, true, true, false><<<dim3(gmx, D_HID / 128), 256, 0, stream>>>(
        h1_bf, W02t, txb, W12t, b2, nullptr, h2_bf, n, D_HID);

    // ---- layer 3: out = (h2@W03 + b3) + A (h2@W13) ----
    k_gemm_dual<D_HID><<<dim3(gmx, 2), 256, 0, stream>>>(
        h2_bf, W03t, W13t, b3, part, y3_bf, n);
    k_agg_bf<D_OUT, false, true, true><<<dim3(gax, 1), 256, 0, stream>>>(
        off, edges, y3_bf, nullptr, out, part, n);
}